// Round 4
// baseline (76.169 us; speedup 1.0000x reference)
//
#include <hip/hip_runtime.h>
#include <math.h>

// NeRF fused volume renderer, MI355X (gfx950) — MFMA + in-register dataflow.
// Wave = ray, batch = 64 samples (2 batches for S=128), col lane&15 = sample-in-tile.
// Round 4: no per-wave LDS activations.
//   * posenc computed directly in B-fragment layout (lane computes feats 8g..8g+7
//     for samples 16nt+lh) — X LDS buffer gone
//   * D->B layer transitions via 2-round shuffle transpose (XOR32 then XOR16)
//   * LDS 56KB -> 23KB, launch_bounds(256,3): 3 blocks/CU, 12 waves/CU
//   * occ-grid gathers for both batches prefetched before the MLP
// Layout facts (m89-verified): C/D col=lane&15, row=(lane>>4)*4+reg;
// A/B row/col=lane&15, k=(lane>>4)*8+e.

typedef _Float16 f16x8 __attribute__((ext_vector_type(8)));
typedef float f32x4 __attribute__((ext_vector_type(4)));

static constexpr float STEPf = 0.040594940802395566f; // 3*sqrt(3)/128 in f32

static __device__ __forceinline__ unsigned pk2(float a, float b) {
    return __builtin_bit_cast(unsigned, __builtin_amdgcn_cvt_pkrtz(a, b));
}
static __device__ __forceinline__ f16x8 mk8(unsigned a, unsigned b, unsigned c, unsigned d) {
    uint4 u = make_uint4(a, b, c, d);
    return __builtin_bit_cast(f16x8, u);
}

// In-register D->B transpose among the 4 lanes {lh, lh+16, lh+32, lh+48}.
// In:  pk[mt] = uint2 of f16 pairs, pk[mt] holds h = 16mt+4g+{0,1 | 2,3} for this lane.
// Out: o0/o1 = B-fragments for k-steps 0/1: dword j of o_ks holds h = 32ks+8g+2j..+1.
static __device__ __forceinline__ void transp(const uint2 pk[4], int lane,
                                              f16x8& o0, f16x8& o1) {
    const bool aHi = (lane & 32) != 0;   // bit5 = g>>1
    const bool cHi = (lane & 16) != 0;   // bit4 = g&1
    // Round 1 (XOR 32): keep values with mt&1 == a, send the rest.
    uint2 keep0, send0, keep1, send1;
    keep0.x = aHi ? pk[1].x : pk[0].x;  keep0.y = aHi ? pk[1].y : pk[0].y;
    send0.x = aHi ? pk[0].x : pk[1].x;  send0.y = aHi ? pk[0].y : pk[1].y;
    keep1.x = aHi ? pk[3].x : pk[2].x;  keep1.y = aHi ? pk[3].y : pk[2].y;
    send1.x = aHi ? pk[2].x : pk[3].x;  send1.y = aHi ? pk[2].y : pk[3].y;
    uint2 rA0, rA1;
    rA0.x = (unsigned)__shfl_xor((int)send0.x, 32);
    rA0.y = (unsigned)__shfl_xor((int)send0.y, 32);
    rA1.x = (unsigned)__shfl_xor((int)send1.x, 32);
    rA1.y = (unsigned)__shfl_xor((int)send1.y, 32);
    // Round 2 (XOR 16): keep values whose origin-a' == c, send the rest.
    const bool ca = (aHi == cHi);
    uint2 k20, s20, k21, s21;
    k20.x = ca ? keep0.x : rA0.x;  k20.y = ca ? keep0.y : rA0.y;
    s20.x = ca ? rA0.x : keep0.x;  s20.y = ca ? rA0.y : keep0.y;
    k21.x = ca ? keep1.x : rA1.x;  k21.y = ca ? keep1.y : rA1.y;
    s21.x = ca ? rA1.x : keep1.x;  s21.y = ca ? rA1.y : keep1.y;
    uint2 rB0, rB1;
    rB0.x = (unsigned)__shfl_xor((int)s20.x, 16);
    rB0.y = (unsigned)__shfl_xor((int)s20.y, 16);
    rB1.x = (unsigned)__shfl_xor((int)s21.x, 16);
    rB1.y = (unsigned)__shfl_xor((int)s21.y, 16);
    // Assemble: kept -> slots 2C..2C+1, received -> slots 2(1-C)..2(1-C)+1.
    o0 = mk8(cHi ? rB0.x : k20.x, cHi ? rB0.y : k20.y,
             cHi ? k20.x : rB0.x, cHi ? k20.y : rB0.y);
    o1 = mk8(cHi ? rB1.x : k21.x, cHi ? rB1.y : k21.y,
             cHi ? k21.x : rB1.x, cHi ? k21.y : rB1.y);
}

extern "C" __global__ void __launch_bounds__(256, 3)
nerf_mfma(const float* __restrict__ rays_o, const float* __restrict__ viewdirs,
          const void* __restrict__ occ,
          const float* __restrict__ W1g, const float* __restrict__ b1g,
          const float* __restrict__ W2g, const float* __restrict__ b2g,
          const float* __restrict__ Wsg, const float* __restrict__ bsg,
          const float* __restrict__ Wcg, const float* __restrict__ Wdg,
          const float* __restrict__ bcg, const float* __restrict__ Wrg,
          const float* __restrict__ brg,
          float* __restrict__ out, int nrays)
{
    // A-operand weights, f16, pre-transposed: sW[h][k], k-contiguous, XOR-swizzled.
    __shared__ __align__(16) unsigned char sW1[64 * 64];    // rows 64B  (K=32), swz (h&3)
    __shared__ __align__(16) unsigned char sW2[64 * 128];   // rows 128B (K=64), swz (h&7)
    __shared__ __align__(16) unsigned char sWc[64 * 128];
    __shared__ __align__(16) float sB1[64], sB2[64], sWs[64];
    __shared__ __align__(16) float sWrR[64], sWrG[64], sWrB[64];
    __shared__ __align__(16) float sPdB[4][64];             // per-wave (pe_d@Wd + bc)
    __shared__ int sKind;

    const int tid = threadIdx.x;

    for (int idx = tid; idx < 64 * 32; idx += 256) {        // W1: A[h][k]=W1[k][h], pad k>=27
        const int h = idx >> 5, k = idx & 31;
        const float v = (k < 27) ? W1g[k * 64 + h] : 0.f;
        *(_Float16*)(sW1 + h * 64 + (((k >> 3) ^ (h & 3)) << 4) + ((k & 7) << 1)) = (_Float16)v;
    }
    for (int idx = tid; idx < 64 * 64; idx += 256) {        // W2, Wc
        const int h = idx >> 6, k = idx & 63;
        const int off = h * 128 + (((k >> 3) ^ (h & 7)) << 4) + ((k & 7) << 1);
        *(_Float16*)(sW2 + off) = (_Float16)W2g[k * 64 + h];
        *(_Float16*)(sWc + off) = (_Float16)Wcg[k * 64 + h];
    }
    if (tid < 64) {
        sB1[tid] = b1g[tid]; sB2[tid] = b2g[tid]; sWs[tid] = Wsg[tid];
        sWrR[tid] = Wrg[tid * 3 + 0]; sWrG[tid] = Wrg[tid * 3 + 1]; sWrB[tid] = Wrg[tid * 3 + 2];
    }
    if (tid == 0) {   // sniff occ dtype: 0=u8, 1=i32, 2=f32
        const int*   oi = (const int*)occ;
        const float* of = (const float*)occ;
        bool i32ok = true, f32ok = true;
        for (int k = 0; k < 64; ++k) {
            if (oi[k] != 0 && oi[k] != 1) i32ok = false;
            const float f = of[k];
            if (!(f == 0.f || f == 1.f)) f32ok = false;
        }
        sKind = i32ok ? 1 : (f32ok ? 2 : 0);
    }
    __syncthreads();

    const int lane = tid & 63;
    const int wib  = tid >> 6;
    const int ray  = (blockIdx.x << 2) | wib;
    if (ray >= nrays) return;
    const int kind = sKind;
    const int lh = lane & 15, g = lane >> 4;

    const float ox = rays_o[ray * 3 + 0], oy = rays_o[ray * 3 + 1], oz = rays_o[ray * 3 + 2];
    const float dxv = viewdirs[ray * 3 + 0], dyv = viewdirs[ray * 3 + 1], dzv = viewdirs[ray * 3 + 2];
    const float sdx = fabsf(dxv) < 1e-8f ? 1e-8f : dxv;
    const float sdy = fabsf(dyv) < 1e-8f ? 1e-8f : dyv;
    const float sdz = fabsf(dzv) < 1e-8f ? 1e-8f : dzv;
    const float t1x = (-1.5f - ox) / sdx, t2x = (1.5f - ox) / sdx;
    const float t1y = (-1.5f - oy) / sdy, t2y = (1.5f - oy) / sdy;
    const float t1z = (-1.5f - oz) / sdz, t2z = (1.5f - oz) / sdz;
    const float t_near = fmaxf(fmaxf(fminf(t1x, t2x), fminf(t1y, t2y)),
                               fmaxf(fminf(t1z, t2z), 0.f));
    const float t_far  = fminf(fminf(fmaxf(t1x, t2x), fmaxf(t1y, t2y)), fmaxf(t1z, t2z));

    // per-ray dir posenc -> sPdB[wib][j] = (pe_d @ Wd)[j] + bc[j]
    {
        float ped[15];
        ped[0] = dxv; ped[1] = dyv; ped[2] = dzv;
        const float dc[3] = {dxv, dyv, dzv};
        #pragma unroll
        for (int c = 0; c < 3; ++c) {
            float s1, c1;
            __sincosf(dc[c], &s1, &c1);
            ped[3 + c * 4 + 0] = s1;
            ped[3 + c * 4 + 1] = 2.f * s1 * c1;
            ped[3 + c * 4 + 2] = c1;
            ped[3 + c * 4 + 3] = 1.f - 2.f * s1 * s1;
        }
        float pd = 0.f;
        #pragma unroll
        for (int i = 0; i < 15; ++i) pd += ped[i] * Wdg[i * 64 + lane];
        sPdB[wib][lane] = pd + bcg[lane];
    }

    const float bsV = bsg[0];
    const float br0 = brg[0], br1 = brg[1], br2 = brg[2];

    // ---- prefetch per-batch own-sample validity + occupancy (both batches) ----
    bool inseg[2], valid[2];
    float tOwn[2];
    {
        int ci[2];
        bool inbox[2];
        #pragma unroll
        for (int b = 0; b < 2; ++b) {
            const float t = t_near + ((float)((b << 6) | lane) + 0.5f) * STEPf;
            tOwn[b] = t;
            inseg[b] = t < t_far;
            const float px = ox + dxv * t, py = oy + dyv * t, pz = oz + dzv * t;
            const float cx = (px + 1.5f) * (128.f / 3.f);
            const float cy = (py + 1.5f) * (128.f / 3.f);
            const float cz = (pz + 1.5f) * (128.f / 3.f);
            inbox[b] = (cx >= 0.f) & (cx < 128.f) & (cy >= 0.f) & (cy < 128.f)
                     & (cz >= 0.f) & (cz < 128.f);
            const int ix = min(max((int)floorf(cx), 0), 127);
            const int iy = min(max((int)floorf(cy), 0), 127);
            const int iz = min(max((int)floorf(cz), 0), 127);
            ci[b] = (ix << 14) | (iy << 7) | iz;
        }
        bool occv[2];
        if (kind == 1) {
            occv[0] = ((const int*)occ)[ci[0]] != 0; occv[1] = ((const int*)occ)[ci[1]] != 0;
        } else if (kind == 2) {
            occv[0] = ((const float*)occ)[ci[0]] != 0.f; occv[1] = ((const float*)occ)[ci[1]] != 0.f;
        } else {
            occv[0] = ((const unsigned char*)occ)[ci[0]] != 0;
            occv[1] = ((const unsigned char*)occ)[ci[1]] != 0;
        }
        valid[0] = inseg[0] & inbox[0] & occv[0];
        valid[1] = inseg[1] & inbox[1] & occv[1];
    }

    float carry = 0.f;
    float aW = 0.f, aWT = 0.f, aR = 0.f, aG = 0.f, aB = 0.f;

    #pragma unroll 1
    for (int b = 0; b < 2; ++b) {
        if (__ballot(inseg[b]) == 0ULL) break;   // samples monotone in t: done

        if (__ballot(valid[b]) != 0ULL) {
            // ---- posenc directly in B-layout: lane computes feats 8g..8g+7
            //      of samples 16nt+lh ----
            f16x8 bx[4];
            #pragma unroll
            for (int nt = 0; nt < 4; ++nt) {
                const float ts = t_near + ((float)((b << 6) + (nt << 4) + lh) + 0.5f) * STEPf;
                const float qx = ox + dxv * ts, qy = oy + dyv * ts, qz = oz + dzv * ts;
                const float u = (g < 2) ? qx : ((g == 2) ? qy : qz);
                const float v = (g == 1) ? qy : ((g == 2) ? qz : 0.f);
                float su1, cu1, sv1, cv1;
                __sincosf(u, &su1, &cu1);
                __sincosf(v, &sv1, &cv1);
                const float su2 = 2.f * su1 * cu1, cu2 = 1.f - 2.f * su1 * su1;
                const float su4 = 2.f * su2 * cu2, cu4 = 1.f - 2.f * su2 * su2;
                const float su8 = 2.f * su4 * cu4, cu8 = 1.f - 2.f * su4 * su4;
                const float sv2 = 2.f * sv1 * cv1, cv2 = 1.f - 2.f * sv1 * sv1;
                const float sv4 = 2.f * sv2 * cv2, cv4 = 1.f - 2.f * sv2 * sv2;
                const float sv8 = 2.f * sv4 * cv4;
                const bool g0 = (g == 0);
                const float f0 = g0 ? qx : cu2;
                const float f1 = g0 ? qy : cu4;
                const float f2 = g0 ? qz : cu8;
                const float f3 = g0 ? su1 : sv1;
                const float f4 = g0 ? su2 : sv2;
                const float f5 = g0 ? su4 : sv4;
                const float f6 = g0 ? su8 : sv8;
                const float f7 = g0 ? cu1 : ((g == 3) ? 0.f : cv1);
                bx[nt] = mk8(pk2(f0, f1), pk2(f2, f3), pk2(f4, f5), pk2(f6, f7));
            }

            f32x4 acc[4][4];
            // ---- L1: K=32, B in registers ----
            #pragma unroll
            for (int mt = 0; mt < 4; ++mt) {
                const f32x4 bf = *(const f32x4*)&sB1[16 * mt + 4 * g];
                const f16x8 a = *(const f16x8*)(sW1 + (16 * mt + lh) * 64 + ((g ^ (lh & 3)) << 4));
                #pragma unroll
                for (int nt = 0; nt < 4; ++nt)
                    acc[mt][nt] = __builtin_amdgcn_mfma_f32_16x16x32_f16(a, bx[nt], bf, 0, 0, 0);
            }
            // relu + pack + transpose -> B-fragments for L2
            f16x8 bhA[4], bhB[4];
            #pragma unroll
            for (int nt = 0; nt < 4; ++nt) {
                uint2 pkv[4];
                #pragma unroll
                for (int mt = 0; mt < 4; ++mt) {
                    f32x4 c = acc[mt][nt];
                    c[0] = fmaxf(c[0], 0.f); c[1] = fmaxf(c[1], 0.f);
                    c[2] = fmaxf(c[2], 0.f); c[3] = fmaxf(c[3], 0.f);
                    pkv[mt].x = pk2(c[0], c[1]); pkv[mt].y = pk2(c[2], c[3]);
                }
                transp(pkv, lane, bhA[nt], bhB[nt]);
            }
            // ---- L2: K=64 (2 k-steps) ----
            #pragma unroll
            for (int mt = 0; mt < 4; ++mt) {
                const f32x4 bf = *(const f32x4*)&sB2[16 * mt + 4 * g];
                #pragma unroll
                for (int nt = 0; nt < 4; ++nt) acc[mt][nt] = bf;
            }
            #pragma unroll
            for (int mt = 0; mt < 4; ++mt) {
                const f16x8 a0 = *(const f16x8*)(sW2 + (16 * mt + lh) * 128 + ((g ^ (lh & 7)) << 4));
                const f16x8 a1 = *(const f16x8*)(sW2 + (16 * mt + lh) * 128 + (((4 + g) ^ (lh & 7)) << 4));
                #pragma unroll
                for (int nt = 0; nt < 4; ++nt) {
                    acc[mt][nt] = __builtin_amdgcn_mfma_f32_16x16x32_f16(a0, bhA[nt], acc[mt][nt], 0, 0, 0);
                    acc[mt][nt] = __builtin_amdgcn_mfma_f32_16x16x32_f16(a1, bhB[nt], acc[mt][nt], 0, 0, 0);
                }
            }
            // relu + sigma partials + pack + transpose
            float sp[4] = {0.f, 0.f, 0.f, 0.f};
            #pragma unroll
            for (int nt = 0; nt < 4; ++nt) {
                uint2 pkv[4];
                #pragma unroll
                for (int mt = 0; mt < 4; ++mt) {
                    const f32x4 ws = *(const f32x4*)&sWs[16 * mt + 4 * g];
                    f32x4 c = acc[mt][nt];
                    c[0] = fmaxf(c[0], 0.f); c[1] = fmaxf(c[1], 0.f);
                    c[2] = fmaxf(c[2], 0.f); c[3] = fmaxf(c[3], 0.f);
                    sp[nt] += ws[0] * c[0] + ws[1] * c[1] + ws[2] * c[2] + ws[3] * c[3];
                    pkv[mt].x = pk2(c[0], c[1]); pkv[mt].y = pk2(c[2], c[3]);
                }
                transp(pkv, lane, bhA[nt], bhB[nt]);
            }
            // ---- Wc layer (init = pd + bc) + rgb head ----
            #pragma unroll
            for (int mt = 0; mt < 4; ++mt) {
                const f32x4 pdf = *(const f32x4*)&sPdB[wib][16 * mt + 4 * g];
                #pragma unroll
                for (int nt = 0; nt < 4; ++nt) acc[mt][nt] = pdf;
            }
            #pragma unroll
            for (int mt = 0; mt < 4; ++mt) {
                const f16x8 a0 = *(const f16x8*)(sWc + (16 * mt + lh) * 128 + ((g ^ (lh & 7)) << 4));
                const f16x8 a1 = *(const f16x8*)(sWc + (16 * mt + lh) * 128 + (((4 + g) ^ (lh & 7)) << 4));
                #pragma unroll
                for (int nt = 0; nt < 4; ++nt) {
                    acc[mt][nt] = __builtin_amdgcn_mfma_f32_16x16x32_f16(a0, bhA[nt], acc[mt][nt], 0, 0, 0);
                    acc[mt][nt] = __builtin_amdgcn_mfma_f32_16x16x32_f16(a1, bhB[nt], acc[mt][nt], 0, 0, 0);
                }
            }
            float cRp[4] = {0.f, 0.f, 0.f, 0.f}, cGp[4] = {0.f, 0.f, 0.f, 0.f}, cBp[4] = {0.f, 0.f, 0.f, 0.f};
            #pragma unroll
            for (int mt = 0; mt < 4; ++mt) {
                const f32x4 wr = *(const f32x4*)&sWrR[16 * mt + 4 * g];
                const f32x4 wg = *(const f32x4*)&sWrG[16 * mt + 4 * g];
                const f32x4 wb = *(const f32x4*)&sWrB[16 * mt + 4 * g];
                #pragma unroll
                for (int nt = 0; nt < 4; ++nt) {
                    f32x4 c = acc[mt][nt];
                    c[0] = fmaxf(c[0], 0.f); c[1] = fmaxf(c[1], 0.f);
                    c[2] = fmaxf(c[2], 0.f); c[3] = fmaxf(c[3], 0.f);
                    cRp[nt] += wr[0] * c[0] + wr[1] * c[1] + wr[2] * c[2] + wr[3] * c[3];
                    cGp[nt] += wg[0] * c[0] + wg[1] * c[1] + wg[2] * c[2] + wg[3] * c[3];
                    cBp[nt] += wb[0] * c[0] + wb[1] * c[1] + wb[2] * c[2] + wb[3] * c[3];
                }
            }
            // ---- cross-lane reduce heads (over g-groups) ----
            #pragma unroll
            for (int nt = 0; nt < 4; ++nt) {
                sp[nt]  += __shfl_xor(sp[nt], 16);  sp[nt]  += __shfl_xor(sp[nt], 32);
                cRp[nt] += __shfl_xor(cRp[nt], 16); cRp[nt] += __shfl_xor(cRp[nt], 32);
                cGp[nt] += __shfl_xor(cGp[nt], 16); cGp[nt] += __shfl_xor(cGp[nt], 32);
                cBp[nt] += __shfl_xor(cBp[nt], 16); cBp[nt] += __shfl_xor(cBp[nt], 32);
            }
            const float sgRaw = (g == 0) ? sp[0] : (g == 1) ? sp[1] : (g == 2) ? sp[2] : sp[3];
            const float crS   = (g == 0) ? cRp[0] : (g == 1) ? cRp[1] : (g == 2) ? cRp[2] : cRp[3];
            const float cgS   = (g == 0) ? cGp[0] : (g == 1) ? cGp[1] : (g == 2) ? cGp[2] : cGp[3];
            const float cbS   = (g == 0) ? cBp[0] : (g == 1) ? cBp[1] : (g == 2) ? cBp[2] : cBp[3];

            const float sigma = valid[b] ? fmaxf(sgRaw + bsV, 0.f) : 0.f;
            const float rC = 1.f / (1.f + __expf(-(crS + br0)));
            const float gC = 1.f / (1.f + __expf(-(cgS + br1)));
            const float bC = 1.f / (1.f + __expf(-(cbS + br2)));

            // ---- compositing: wave inclusive scan ----
            const float sdelta = sigma * STEPf;
            float scan = sdelta;
            #pragma unroll
            for (int off = 1; off < 64; off <<= 1) {
                const float n = __shfl_up(scan, off);
                if (lane >= off) scan += n;
            }
            const float T     = __expf(-(carry + scan - sdelta));
            const float alpha = 1.f - __expf(-sdelta);
            const float w = T * alpha;
            aW  += w;
            aWT += w * tOwn[b];
            aR  += w * rC;
            aG  += w * gC;
            aB  += w * bC;
            carry += __shfl(scan, 63);
            if (carry > 12.f) break;   // T < 6e-6: rest negligible
        }
    }

    // ---- reduce across lanes + store ----
    #pragma unroll
    for (int off = 32; off; off >>= 1) {
        aW  += __shfl_xor(aW,  off);
        aWT += __shfl_xor(aWT, off);
        aR  += __shfl_xor(aR,  off);
        aG  += __shfl_xor(aG,  off);
        aB  += __shfl_xor(aB,  off);
    }
    if (lane == 0) {
        const float bg = 1.f - aW;
        out[ray * 3 + 0] = aR + bg;
        out[ray * 3 + 1] = aG + bg;
        out[ray * 3 + 2] = aB + bg;
        out[3 * nrays + ray] = aWT;
        out[4 * nrays + ray] = aW;
    }
}

extern "C" void kernel_launch(void* const* d_in, const int* in_sizes, int n_in,
                              void* d_out, int out_size, void* d_ws, size_t ws_size,
                              hipStream_t stream) {
    const float* rays_o   = (const float*)d_in[0];
    const float* viewdirs = (const float*)d_in[1];
    const void*  occ      = (const void*) d_in[2];
    const float* W1 = (const float*)d_in[3];
    const float* b1 = (const float*)d_in[4];
    const float* W2 = (const float*)d_in[5];
    const float* b2 = (const float*)d_in[6];
    const float* Ws = (const float*)d_in[7];
    const float* bs = (const float*)d_in[8];
    const float* Wc = (const float*)d_in[9];
    const float* Wd = (const float*)d_in[10];
    const float* bc = (const float*)d_in[11];
    const float* Wr = (const float*)d_in[12];
    const float* br = (const float*)d_in[13];
    float* out = (float*)d_out;

    const int nrays = in_sizes[0] / 3;
    const int nblocks = (nrays + 3) / 4;   // 4 rays (waves) per 256-thread block

    nerf_mfma<<<nblocks, 256, 0, stream>>>(rays_o, viewdirs, occ,
                                           W1, b1, W2, b2, Ws, bs, Wc, Wd, bc, Wr, br,
                                           out, nrays);
}